// Round 10
// baseline (120.102 us; speedup 1.0000x reference)
//
#include <hip/hip_runtime.h>

// TrainableButterfly: LENGTH=2048 (11 levels), BATCH=4096.
// CROSS_T=1.0, CROSS_PHI=0.0 -> crossings are identity; in natural storage order
// level l = butterfly on slots (c, c + 2^{10-l}), in place; final order natural.
// Pair-twiddle index for lower slot c at level l:
//   p(c,l) = (rev_{10-l}(c & (2^{10-l}-1)) << l) | (c >> (11-l))
//
// R10: WAVE-LOCAL structure — zero LDS, zero barriers. One wave = one row.
// Lane l holds the 32 complexes c = (k<<7)|(l<<1)|b0 (k in [0,16), b0 in {0,1}),
// i.e. j = 2k+b0 in [0,32), from its own coalesced float4 loads (unit k*64+l).
//   bit(10-L) of c:  L0..L3 -> j bits 4..1 (register-local pairs D=16,8,4,2)
//                    L4..L9 -> lane bits 5..0 (shfl_xor mask 32..1, product-exchange)
//                    L10    -> j bit 0 (register-local pairs D=1)
// Each wave is an independent dataflow: twiddle loads || fma || shfl, no walls.
//
// tw layout (float4 index): section s in [0,12): [s*1024 + i*64 + l], i in [0,16).
//   s = L in [0,11): level-L twiddles for lane l's i-th pair (local levels:
//       (cos t1, sin t1, cos t2, sin t2) of the pair's lower slot) or i-th
//       complex-duo (shfl levels / s=11 pointwise: side-baked (cos,sin) x2).

__device__ __forceinline__ unsigned revw(unsigned x, int w) {
    return w ? (__brev(x) >> (32 - w)) : 0u;
}
__device__ __forceinline__ unsigned pmap(unsigned slot, int level) {
    int shift = 10 - level;
    return (revw(slot & ((1u << shift) - 1u), shift) << level) | (slot >> (shift + 1));
}
// complex index for (j, lane): c = ((j>>1)<<7) | (lane<<1) | (j&1)
__device__ __forceinline__ unsigned cidx(unsigned j, unsigned l) {
    return ((j >> 1) << 7) | (l << 1) | (j & 1);
}

__global__ void twiddle_kernel(const float* __restrict__ phases, float4* __restrict__ tw) {
    int id = blockIdx.x * 256 + threadIdx.x;
    if (id >= 12288) return;
    int sec = id >> 10;            // 0..11
    int rem = id & 1023;
    unsigned i = (unsigned)(rem >> 6);
    unsigned l = (unsigned)(rem & 63);
    float4 v;
    if (sec < 11) {
        int L = sec;
        if (L <= 3 || L == 10) {   // register-local level: full pair twiddle
            unsigned D = (L == 10) ? 1u : (16u >> L);
            unsigned lo = i & (D - 1u), hi = i / D;
            unsigned jlo = hi * 2u * D + lo;
            unsigned c = cidx(jlo, l);
            unsigned p = pmap(c, L);
            const float* ph = phases + (L * 1024 + p) * 2;
            float t1 = ph[0], t2 = ph[1];
            v = make_float4(cosf(t1), sinf(t1), cosf(t2), sinf(t2));
        } else {                   // shfl level: side-baked theta for complexes 2i, 2i+1
            unsigned bit = 1u << (10 - L);
            unsigned c0 = cidx(2 * i, l), c1 = cidx(2 * i + 1, l);
            float th0 = phases[(L * 1024 + pmap(c0 & ~bit, L)) * 2 + ((c0 >> (10 - L)) & 1)];
            float th1 = phases[(L * 1024 + pmap(c1 & ~bit, L)) * 2 + ((c1 >> (10 - L)) & 1)];
            v = make_float4(cosf(th0), sinf(th0), cosf(th1), sinf(th1));
        }
    } else {                       // pointwise e^{i lp(c)} for complexes 2i, 2i+1
        unsigned c0 = cidx(2 * i, l), c1 = cidx(2 * i + 1, l);
        float a = phases[11 * 2048 + c0], b = phases[11 * 2048 + c1];
        v = make_float4(cosf(a), sinf(a), cosf(b), sinf(b));
    }
    tw[id] = v;
}

// butterfly: o0 = e^{i t1} v0 + i e^{i t2} v1 ; o1 = i e^{i t1} v0 + e^{i t2} v1
__device__ __forceinline__ void bf(float2 v0, float2 v1, float4 w, float2& o0, float2& o1) {
    float ar = fmaf(w.x, v0.x, -w.y * v0.y);
    float ai = fmaf(w.x, v0.y,  w.y * v0.x);
    float br = fmaf(w.z, v1.x, -w.w * v1.y);
    float bi = fmaf(w.z, v1.y,  w.w * v1.x);
    o0 = make_float2(ar - bi, ai + br);
    o1 = make_float2(br - ai, bi + ar);
}
__device__ __forceinline__ float2 cm(float wc, float ws, float2 z) {
    return make_float2(fmaf(wc, z.x, -ws * z.y), fmaf(wc, z.y, ws * z.x));
}
// both sides of an exchanged butterfly: o = local + i * recv
__device__ __forceinline__ float2 comb(float2 local, float2 recv) {
    return make_float2(local.x - recv.y, local.y + recv.x);
}
__device__ __forceinline__ float2 sx(float2 v, int mask) {
    return make_float2(__shfl_xor(v.x, mask, 64), __shfl_xor(v.y, mask, 64));
}

template <int L, int D>
__device__ __forceinline__ void local_level(float2 z[32], const float4* __restrict__ tw,
                                            unsigned l) {
#pragma unroll
    for (int i = 0; i < 16; ++i) {
        float4 w = tw[L * 1024 + i * 64 + l];
        constexpr int DM = D;
        int lo = (i / DM) * 2 * DM + (i % DM);
        bf(z[lo], z[lo + DM], w, z[lo], z[lo + DM]);
    }
}

template <int L>
__device__ __forceinline__ void shfl_level(float2 z[32], const float4* __restrict__ tw,
                                           unsigned l) {
    constexpr int m = 1 << (9 - L);
#pragma unroll
    for (int i = 0; i < 16; ++i) {
        float4 w = tw[L * 1024 + i * 64 + l];
        float2 a0 = cm(w.x, w.y, z[2 * i]);
        float2 a1 = cm(w.z, w.w, z[2 * i + 1]);
        z[2 * i]     = comb(a0, sx(a0, m));
        z[2 * i + 1] = comb(a1, sx(a1, m));
    }
}

__global__ __launch_bounds__(256, 4) void bfly_kernel(const float4* __restrict__ x,
                                                      const float4* __restrict__ tw,
                                                      float4* __restrict__ out) {
    const unsigned tid = threadIdx.x;
    const unsigned l = tid & 63u;
    const int row = blockIdx.x * 4 + (int)(tid >> 6);   // one wave = one row
    const float4* xr = x + (size_t)row * 1024;
    float4* outr = out + (size_t)row * 1024;

    float2 z[32];
#pragma unroll
    for (int k = 0; k < 16; ++k) {                      // coalesced: unit k*64+l
        float4 q = xr[k * 64 + l];
        z[2 * k]     = make_float2(q.x, q.y);
        z[2 * k + 1] = make_float2(q.z, q.w);
    }

    local_level<0, 16>(z, tw, l);    // level 0: c-bit 10 (j bit 4)
    local_level<1, 8>(z, tw, l);     // level 1: j bit 3
    local_level<2, 4>(z, tw, l);     // level 2: j bit 2
    local_level<3, 2>(z, tw, l);     // level 3: j bit 1

    shfl_level<4>(z, tw, l);         // lane bit 5 (mask 32)
    shfl_level<5>(z, tw, l);         // mask 16
    shfl_level<6>(z, tw, l);         // mask 8
    shfl_level<7>(z, tw, l);         // mask 4
    shfl_level<8>(z, tw, l);         // mask 2
    shfl_level<9>(z, tw, l);         // mask 1

    local_level<10, 1>(z, tw, l);    // level 10: j bit 0

    // pointwise + coalesced store
#pragma unroll
    for (int i = 0; i < 16; ++i) {
        float4 p = tw[11 * 1024 + i * 64 + l];
        float2 r0 = cm(p.x, p.y, z[2 * i]);
        float2 r1 = cm(p.z, p.w, z[2 * i + 1]);
        outr[i * 64 + l] = make_float4(r0.x, r0.y, r1.x, r1.y);
    }
}

extern "C" void kernel_launch(void* const* d_in, const int* in_sizes, int n_in,
                              void* d_out, int out_size, void* d_ws, size_t ws_size,
                              hipStream_t stream) {
    const float* x = (const float*)d_in[0];        // (4096, 2048, 2) f32
    const float* phases = (const float*)d_in[1];   // (12, 1024, 2) f32
    float4* tw = (float4*)d_ws;                    // 192 KB

    twiddle_kernel<<<48, 256, 0, stream>>>(phases, tw);
    bfly_kernel<<<1024, 256, 0, stream>>>((const float4*)x, tw, (float4*)d_out);
}